// Round 1
// baseline (281.588 us; speedup 1.0000x reference)
//
#include <hip/hip_runtime.h>
#include <hip/hip_bf16.h>

#define E 768
#define HD 64
#define NH 12
#define BSZ 2
#define SEQ 2048
#define M_ROWS (BSZ * SEQ)   // 4096
#define BH (BSZ * NH)        // 24

typedef float f4_t __attribute__((ext_vector_type(4)));
typedef __bf16 bf8_t __attribute__((ext_vector_type(8)));
typedef unsigned short us8_t __attribute__((ext_vector_type(8)));

__device__ inline unsigned short f2bf(float f) {
  union { float f; unsigned u; } v; v.f = f;
  unsigned u = v.u + 0x7FFFu + ((v.u >> 16) & 1u);
  return (unsigned short)(u >> 16);
}

// ---------------- fp32 -> bf16 convert (with scale fold) ----------------
__global__ __launch_bounds__(256) void cvt_bf16(const float* __restrict__ src,
                                                unsigned short* __restrict__ dst,
                                                int n, float scale) {
  int i = (blockIdx.x * 256 + threadIdx.x) * 8;
  if (i >= n) return;
  const float4* s = (const float4*)(src + i);
  float4 a = s[0], b = s[1];
  us8_t o;
  o[0] = f2bf(a.x * scale); o[1] = f2bf(a.y * scale);
  o[2] = f2bf(a.z * scale); o[3] = f2bf(a.w * scale);
  o[4] = f2bf(b.x * scale); o[5] = f2bf(b.y * scale);
  o[6] = f2bf(b.z * scale); o[7] = f2bf(b.w * scale);
  *(us8_t*)(dst + i) = o;
}

// ---------------- fused QKV GEMM: C = X @ Wqkv^T, remapped epilogue ------
// A [4096][768] bf16 row-major, Bw [2304][768] bf16 row-major (B^T style).
// 128x128 tile, BK=32, 4 waves, each wave 64x64 (4x4 of 16x16x32 MFMA).
__global__ __launch_bounds__(256) void gemm_qkv(
    const unsigned short* __restrict__ A, const unsigned short* __restrict__ Bw,
    const float* __restrict__ bq, const float* __restrict__ bk, const float* __restrict__ bv,
    unsigned short* __restrict__ Qb, unsigned short* __restrict__ Kb,
    unsigned short* __restrict__ Vb) {
  __shared__ unsigned short Alds[128 * 32];
  __shared__ unsigned short Blds[128 * 32];
  const int w = threadIdx.x >> 6, lane = threadIdx.x & 63;
  const int quad = lane >> 4, l15 = lane & 15;
  const int rowBase = blockIdx.x * 128;
  const int colBase = blockIdx.y * 128;
  const int wr = (w & 1) * 64, wc = (w >> 1) * 64;
  f4_t acc[4][4] = {};

  for (int k0 = 0; k0 < E; k0 += 32) {
    __syncthreads();
#pragma unroll
    for (int c = 0; c < 2; ++c) {
      int idx = (w * 2 + c) * 512 + lane * 8;  // element within 128x32 tile
      const unsigned short* ga = A + (size_t)(rowBase + (idx >> 5)) * E + k0 + (idx & 31);
      __builtin_amdgcn_global_load_lds((const __attribute__((address_space(1))) void*)ga,
          (__attribute__((address_space(3))) void*)&Alds[(w * 2 + c) * 512], 16, 0, 0);
      const unsigned short* gb = Bw + (size_t)(colBase + (idx >> 5)) * E + k0 + (idx & 31);
      __builtin_amdgcn_global_load_lds((const __attribute__((address_space(1))) void*)gb,
          (__attribute__((address_space(3))) void*)&Blds[(w * 2 + c) * 512], 16, 0, 0);
    }
    __builtin_amdgcn_s_waitcnt(0);
    __syncthreads();
    bf8_t af[4], bfr[4];
#pragma unroll
    for (int mi = 0; mi < 4; ++mi)
      af[mi] = *(const bf8_t*)&Alds[(wr + mi * 16 + l15) * 32 + quad * 8];
#pragma unroll
    for (int ni = 0; ni < 4; ++ni)
      bfr[ni] = *(const bf8_t*)&Blds[(wc + ni * 16 + l15) * 32 + quad * 8];
#pragma unroll
    for (int mi = 0; mi < 4; ++mi)
#pragma unroll
      for (int ni = 0; ni < 4; ++ni)
        acc[mi][ni] = __builtin_amdgcn_mfma_f32_16x16x32_bf16(af[mi], bfr[ni], acc[mi][ni], 0, 0, 0);
  }

  // epilogue: col -> (which, h, d); row -> (b, t); write [bh][t][d] bf16
  const int which = colBase / E;  // 128 | 768, so uniform per block
  const float* biasP = (which == 0) ? bq : (which == 1 ? bk : bv);
  unsigned short* dst = (which == 0) ? Qb : (which == 1 ? Kb : Vb);
  const float bscale = (which == 0) ? 0.125f : 1.0f;  // fold q scaling into bias too
#pragma unroll
  for (int mi = 0; mi < 4; ++mi) {
#pragma unroll
    for (int ni = 0; ni < 4; ++ni) {
      int gn = colBase + wc + ni * 16 + l15;
      int cn = gn - which * E;
      int h = cn >> 6, d = cn & 63;
      float bias = biasP[cn] * bscale;
#pragma unroll
      for (int r = 0; r < 4; ++r) {
        int gm = rowBase + wr + mi * 16 + quad * 4 + r;  // D: row=(lane>>4)*4+r
        int b = gm >> 11, t = gm & 2047;
        dst[((size_t)(b * NH + h) * SEQ + t) * HD + d] = f2bf(acc[mi][ni][r] + bias);
      }
    }
  }
}

// ---------------- output projection GEMM -> fp32 out ----------------
__global__ __launch_bounds__(256) void gemm_out(
    const unsigned short* __restrict__ A, const unsigned short* __restrict__ Bw,
    const float* __restrict__ bo, float* __restrict__ out) {
  __shared__ unsigned short Alds[128 * 32];
  __shared__ unsigned short Blds[128 * 32];
  const int w = threadIdx.x >> 6, lane = threadIdx.x & 63;
  const int quad = lane >> 4, l15 = lane & 15;
  const int rowBase = blockIdx.x * 128;
  const int colBase = blockIdx.y * 128;
  const int wr = (w & 1) * 64, wc = (w >> 1) * 64;
  f4_t acc[4][4] = {};

  for (int k0 = 0; k0 < E; k0 += 32) {
    __syncthreads();
#pragma unroll
    for (int c = 0; c < 2; ++c) {
      int idx = (w * 2 + c) * 512 + lane * 8;
      const unsigned short* ga = A + (size_t)(rowBase + (idx >> 5)) * E + k0 + (idx & 31);
      __builtin_amdgcn_global_load_lds((const __attribute__((address_space(1))) void*)ga,
          (__attribute__((address_space(3))) void*)&Alds[(w * 2 + c) * 512], 16, 0, 0);
      const unsigned short* gb = Bw + (size_t)(colBase + (idx >> 5)) * E + k0 + (idx & 31);
      __builtin_amdgcn_global_load_lds((const __attribute__((address_space(1))) void*)gb,
          (__attribute__((address_space(3))) void*)&Blds[(w * 2 + c) * 512], 16, 0, 0);
    }
    __builtin_amdgcn_s_waitcnt(0);
    __syncthreads();
    bf8_t af[4], bfr[4];
#pragma unroll
    for (int mi = 0; mi < 4; ++mi)
      af[mi] = *(const bf8_t*)&Alds[(wr + mi * 16 + l15) * 32 + quad * 8];
#pragma unroll
    for (int ni = 0; ni < 4; ++ni)
      bfr[ni] = *(const bf8_t*)&Blds[(wc + ni * 16 + l15) * 32 + quad * 8];
#pragma unroll
    for (int mi = 0; mi < 4; ++mi)
#pragma unroll
      for (int ni = 0; ni < 4; ++ni)
        acc[mi][ni] = __builtin_amdgcn_mfma_f32_16x16x32_bf16(af[mi], bfr[ni], acc[mi][ni], 0, 0, 0);
  }

#pragma unroll
  for (int mi = 0; mi < 4; ++mi) {
#pragma unroll
    for (int ni = 0; ni < 4; ++ni) {
      int gn = colBase + wc + ni * 16 + l15;
      float bias = bo[gn];
#pragma unroll
      for (int r = 0; r < 4; ++r) {
        int gm = rowBase + wr + mi * 16 + quad * 4 + r;
        out[(size_t)gm * E + gn] = acc[mi][ni][r] + bias;
      }
    }
  }
}

// ---------------- flash attention ----------------
// grid (32 q-tiles, 24 bh). 64 queries/block, 4 waves x 16 rows. 64-wide s-tiles.
__global__ __launch_bounds__(256) void flash_attn(
    const unsigned short* __restrict__ Qb, const unsigned short* __restrict__ Kb,
    const unsigned short* __restrict__ Vb, const float* __restrict__ biasArr,
    const float* __restrict__ mask, const float* __restrict__ betaP,
    const float* __restrict__ betabP, unsigned short* __restrict__ attn) {
  __shared__ unsigned short Klds[64 * 64];     // [s][d]
  __shared__ unsigned short Vt[64 * 72];       // [d][s], stride 72 (16B-aligned, bank-spread)
  __shared__ unsigned short Plds[4][16 * 64];  // per-wave P round-trip
  const int w = threadIdx.x >> 6, lane = threadIdx.x & 63;
  const int quad = lane >> 4, l15 = lane & 15;
  const int qt = blockIdx.x, bh = blockIdx.y;
  const int b = bh / NH, h = bh % NH;
  const int q0 = qt * 64;
  const float betav = betaP[0], betabv = betabP[0];

  // Q fragments (A-layout: m=l15, k=quad*8+j), held in regs for whole s-loop
  const unsigned short* qbase = Qb + ((size_t)bh * SEQ + q0 + w * 16 + l15) * HD;
  bf8_t qf[2];
  qf[0] = *(const bf8_t*)(qbase + quad * 8);
  qf[1] = *(const bf8_t*)(qbase + 32 + quad * 8);

  float m_i[4], l_i[4];
  f4_t Oacc[4] = {};
#pragma unroll
  for (int r = 0; r < 4; ++r) { m_i[r] = -1e30f; l_i[r] = 0.f; }

  const size_t ktile_base = (size_t)bh * SEQ * HD;

  for (int s0 = 0; s0 < SEQ; s0 += 64) {
    __syncthreads();
    // stage K tile (contiguous in global): direct-to-LDS
#pragma unroll
    for (int c = 0; c < 2; ++c) {
      int idx = (w * 2 + c) * 512 + lane * 8;
      const unsigned short* gk = Kb + ktile_base + (size_t)s0 * HD + idx;
      __builtin_amdgcn_global_load_lds((const __attribute__((address_space(1))) void*)gk,
          (__attribute__((address_space(3))) void*)&Klds[(w * 2 + c) * 512], 16, 0, 0);
    }
    // stage V transposed: each thread 2 x (8 contiguous d of one s-row)
#pragma unroll
    for (int j = 0; j < 2; ++j) {
      int lin = (int)threadIdx.x * 2 + j;  // 0..511
      int s = lin >> 3, dc = (lin & 7) * 8;
      us8_t vv = *(const us8_t*)(Vb + ktile_base + (size_t)(s0 + s) * HD + dc);
#pragma unroll
      for (int i = 0; i < 8; ++i) Vt[(dc + i) * 72 + s] = vv[i];
    }
    __builtin_amdgcn_s_waitcnt(0);
    __syncthreads();

    // S = Q K^T  (B-operand: n=s from Klds rows)
    f4_t sacc[4];
#pragma unroll
    for (int st = 0; st < 4; ++st) {
      sacc[st] = (f4_t){0.f, 0.f, 0.f, 0.f};
#pragma unroll
      for (int ks = 0; ks < 2; ++ks) {
        bf8_t kf = *(const bf8_t*)&Klds[(st * 16 + l15) * 64 + ks * 32 + quad * 8];
        sacc[st] = __builtin_amdgcn_mfma_f32_16x16x32_bf16(qf[ks], kf, sacc[st], 0, 0, 0);
      }
    }

    // score = S + beta*bias[bh,s] + beta_bias + mask[b,q,s]
    float sval[4][4], bb[4];
#pragma unroll
    for (int st = 0; st < 4; ++st)
      bb[st] = betav * biasArr[(size_t)bh * SEQ + s0 + st * 16 + l15] + betabv;
#pragma unroll
    for (int r = 0; r < 4; ++r) {
      int q = q0 + w * 16 + quad * 4 + r;
      const float* mrow = mask + ((size_t)b * SEQ + q) * SEQ + s0;
#pragma unroll
      for (int st = 0; st < 4; ++st)
        sval[st][r] = sacc[st][r] + bb[st] + mrow[st * 16 + l15];
    }

    // online softmax (rows live across 16 lanes of a quad-group)
#pragma unroll
    for (int r = 0; r < 4; ++r) {
      float mx = fmaxf(fmaxf(sval[0][r], sval[1][r]), fmaxf(sval[2][r], sval[3][r]));
#pragma unroll
      for (int off = 1; off < 16; off <<= 1) mx = fmaxf(mx, __shfl_xor(mx, off, 16));
      float mnew = fmaxf(m_i[r], mx);
      float alpha = __expf(m_i[r] - mnew);
      float lsum = 0.f;
#pragma unroll
      for (int st = 0; st < 4; ++st) {
        float p = __expf(sval[st][r] - mnew);
        sval[st][r] = p;
        lsum += p;
      }
#pragma unroll
      for (int off = 1; off < 16; off <<= 1) lsum += __shfl_xor(lsum, off, 16);
      m_i[r] = mnew;
      l_i[r] = l_i[r] * alpha + lsum;
#pragma unroll
      for (int dt = 0; dt < 4; ++dt) Oacc[dt][r] *= alpha;
    }

    // P: C/D-layout -> LDS [q][s] -> re-read in A-layout (m120 pattern)
    unsigned short* Pw = Plds[w];
#pragma unroll
    for (int r = 0; r < 4; ++r)
#pragma unroll
      for (int st = 0; st < 4; ++st)
        Pw[(quad * 4 + r) * 64 + st * 16 + l15] = f2bf(sval[st][r]);

    // O += P @ V   (B-operand: n=d from Vt rows)
#pragma unroll
    for (int ks = 0; ks < 2; ++ks) {
      bf8_t pf = *(const bf8_t*)&Pw[l15 * 64 + ks * 32 + quad * 8];
#pragma unroll
      for (int dt = 0; dt < 4; ++dt) {
        bf8_t vf = *(const bf8_t*)&Vt[(dt * 16 + l15) * 72 + ks * 32 + quad * 8];
        Oacc[dt] = __builtin_amdgcn_mfma_f32_16x16x32_bf16(pf, vf, Oacc[dt], 0, 0, 0);
      }
    }
  }

  // epilogue: O/l -> attn[b*SEQ+t][h*64+d] bf16
#pragma unroll
  for (int r = 0; r < 4; ++r) {
    float inv = 1.0f / l_i[r];
    int q = q0 + w * 16 + quad * 4 + r;
    unsigned short* orow = attn + ((size_t)b * SEQ + q) * E + h * HD;
#pragma unroll
    for (int dt = 0; dt < 4; ++dt) orow[dt * 16 + l15] = f2bf(Oacc[dt][r] * inv);
  }
}

extern "C" void kernel_launch(void* const* d_in, const int* in_sizes, int n_in,
                              void* d_out, int out_size, void* d_ws, size_t ws_size,
                              hipStream_t stream) {
  const float* hidden = (const float*)d_in[0];
  const float* mask = (const float*)d_in[1];
  const float* abias = (const float*)d_in[2];
  const float* Wq = (const float*)d_in[3];
  const float* bq = (const float*)d_in[4];
  const float* Wk = (const float*)d_in[5];
  const float* bk = (const float*)d_in[6];
  const float* Wv = (const float*)d_in[7];
  const float* bv = (const float*)d_in[8];
  const float* Wo = (const float*)d_in[9];
  const float* bo = (const float*)d_in[10];
  const float* beta = (const float*)d_in[11];
  const float* beta_bias = (const float*)d_in[12];
  float* out = (float*)d_out;

  char* ws = (char*)d_ws;
  // layout (bytes): Xbf 6291456 | Wqkv 3538944 | Wobf 1179648 | Q/K/V 3x6291456
  unsigned short* Xbf = (unsigned short*)(ws);
  unsigned short* Wqkv = (unsigned short*)(ws + 6291456);
  unsigned short* Wobf = (unsigned short*)(ws + 9830400);
  unsigned short* Qbuf = (unsigned short*)(ws + 11010048);
  unsigned short* Kbuf = (unsigned short*)(ws + 17301504);
  unsigned short* Vbuf = (unsigned short*)(ws + 23592960);
  unsigned short* Attn = Xbf;  // Xbf dead after gemm_qkv; reuse for attn output

  const int nX = M_ROWS * E;  // 3145728
  const int nW = E * E;       // 589824
  cvt_bf16<<<nX / 2048, 256, 0, stream>>>(hidden, Xbf, nX, 1.0f);
  cvt_bf16<<<nW / 2048, 256, 0, stream>>>(Wq, Wqkv, nW, 0.125f);  // fold 1/sqrt(64)
  cvt_bf16<<<nW / 2048, 256, 0, stream>>>(Wk, Wqkv + nW, nW, 1.0f);
  cvt_bf16<<<nW / 2048, 256, 0, stream>>>(Wv, Wqkv + 2 * nW, nW, 1.0f);
  cvt_bf16<<<nW / 2048, 256, 0, stream>>>(Wo, Wobf, nW, 1.0f);

  gemm_qkv<<<dim3(32, 18), 256, 0, stream>>>(Xbf, Wqkv, bq, bk, bv, Qbuf, Kbuf, Vbuf);
  flash_attn<<<dim3(32, 24), 256, 0, stream>>>(Qbuf, Kbuf, Vbuf, abias, mask, beta, beta_bias, Attn);
  gemm_out<<<dim3(32, 6), 256, 0, stream>>>(Attn, Wobf, bo, out);
}

// Round 2
// 279.782 us; speedup vs baseline: 1.0065x; 1.0065x over previous
//
#include <hip/hip_runtime.h>
#include <hip/hip_bf16.h>

#define E 768
#define HD 64
#define NH 12
#define BSZ 2
#define SEQ 2048
#define M_ROWS (BSZ * SEQ)   // 4096
#define BH (BSZ * NH)        // 24

typedef float f4_t __attribute__((ext_vector_type(4)));
typedef __bf16 bf8_t __attribute__((ext_vector_type(8)));
typedef unsigned short us8_t __attribute__((ext_vector_type(8)));

__device__ inline unsigned short f2bf(float f) {
  union { float f; unsigned u; } v; v.f = f;
  unsigned u = v.u + 0x7FFFu + ((v.u >> 16) & 1u);
  return (unsigned short)(u >> 16);
}

// ---------------- fused fp32 -> bf16 convert for all 5 tensors ----------------
// blocks 0..1535: X (3145728 elts); then 4 x 288 blocks for Wq(scaled)/Wk/Wv/Wo.
__global__ __launch_bounds__(256) void cvt_all(
    const float* __restrict__ X, const float* __restrict__ Wq,
    const float* __restrict__ Wk, const float* __restrict__ Wv,
    const float* __restrict__ Wo, unsigned short* __restrict__ Xbf,
    unsigned short* __restrict__ Wqkv, unsigned short* __restrict__ Wobf) {
  const int nW = E * E;  // 589824
  int id = blockIdx.x;
  const float* src;
  unsigned short* dst;
  float scale = 1.0f;
  int base;
  if (id < 1536) {
    src = X; dst = Xbf; base = id * 2048;
  } else {
    int r = id - 1536;
    int k = r / 288;
    int rb = r - k * 288;
    base = rb * 2048;
    if (k == 0)      { src = Wq; dst = Wqkv;          scale = 0.125f; }
    else if (k == 1) { src = Wk; dst = Wqkv + nW;     }
    else if (k == 2) { src = Wv; dst = Wqkv + 2 * nW; }
    else             { src = Wo; dst = Wobf;          }
  }
  int i = base + threadIdx.x * 8;
  const float4* s = (const float4*)(src + i);
  float4 a = s[0], b = s[1];
  us8_t o;
  o[0] = f2bf(a.x * scale); o[1] = f2bf(a.y * scale);
  o[2] = f2bf(a.z * scale); o[3] = f2bf(a.w * scale);
  o[4] = f2bf(b.x * scale); o[5] = f2bf(b.y * scale);
  o[6] = f2bf(b.z * scale); o[7] = f2bf(b.w * scale);
  *(us8_t*)(dst + i) = o;
}

// ---------------- fused QKV GEMM: C = X @ Wqkv^T, remapped epilogue ------
__global__ __launch_bounds__(256) void gemm_qkv(
    const unsigned short* __restrict__ A, const unsigned short* __restrict__ Bw,
    const float* __restrict__ bq, const float* __restrict__ bk, const float* __restrict__ bv,
    unsigned short* __restrict__ Qb, unsigned short* __restrict__ Kb,
    unsigned short* __restrict__ Vb) {
  __shared__ unsigned short Alds[128 * 32];
  __shared__ unsigned short Blds[128 * 32];
  const int w = threadIdx.x >> 6, lane = threadIdx.x & 63;
  const int quad = lane >> 4, l15 = lane & 15;
  const int rowBase = blockIdx.x * 128;
  const int colBase = blockIdx.y * 128;
  const int wr = (w & 1) * 64, wc = (w >> 1) * 64;
  f4_t acc[4][4] = {};

  for (int k0 = 0; k0 < E; k0 += 32) {
    __syncthreads();
#pragma unroll
    for (int c = 0; c < 2; ++c) {
      int idx = (w * 2 + c) * 512 + lane * 8;
      const unsigned short* ga = A + (size_t)(rowBase + (idx >> 5)) * E + k0 + (idx & 31);
      __builtin_amdgcn_global_load_lds((const __attribute__((address_space(1))) void*)ga,
          (__attribute__((address_space(3))) void*)&Alds[(w * 2 + c) * 512], 16, 0, 0);
      const unsigned short* gb = Bw + (size_t)(colBase + (idx >> 5)) * E + k0 + (idx & 31);
      __builtin_amdgcn_global_load_lds((const __attribute__((address_space(1))) void*)gb,
          (__attribute__((address_space(3))) void*)&Blds[(w * 2 + c) * 512], 16, 0, 0);
    }
    __builtin_amdgcn_s_waitcnt(0);
    __syncthreads();
    bf8_t af[4], bfr[4];
#pragma unroll
    for (int mi = 0; mi < 4; ++mi)
      af[mi] = *(const bf8_t*)&Alds[(wr + mi * 16 + l15) * 32 + quad * 8];
#pragma unroll
    for (int ni = 0; ni < 4; ++ni)
      bfr[ni] = *(const bf8_t*)&Blds[(wc + ni * 16 + l15) * 32 + quad * 8];
#pragma unroll
    for (int mi = 0; mi < 4; ++mi)
#pragma unroll
      for (int ni = 0; ni < 4; ++ni)
        acc[mi][ni] = __builtin_amdgcn_mfma_f32_16x16x32_bf16(af[mi], bfr[ni], acc[mi][ni], 0, 0, 0);
  }

  const int which = colBase / E;
  const float* biasP = (which == 0) ? bq : (which == 1 ? bk : bv);
  unsigned short* dst = (which == 0) ? Qb : (which == 1 ? Kb : Vb);
  const float bscale = (which == 0) ? 0.125f : 1.0f;
#pragma unroll
  for (int mi = 0; mi < 4; ++mi) {
#pragma unroll
    for (int ni = 0; ni < 4; ++ni) {
      int gn = colBase + wc + ni * 16 + l15;
      int cn = gn - which * E;
      int h = cn >> 6, d = cn & 63;
      float bias = biasP[cn] * bscale;
#pragma unroll
      for (int r = 0; r < 4; ++r) {
        int gm = rowBase + wr + mi * 16 + quad * 4 + r;
        int b = gm >> 11, t = gm & 2047;
        dst[((size_t)(b * NH + h) * SEQ + t) * HD + d] = f2bf(acc[mi][ni][r] + bias);
      }
    }
  }
}

// ---------------- V [bh][t][d] -> V^T [bh][d][t] (LDS-tiled) ----------------
__global__ __launch_bounds__(256) void vtrans(const unsigned short* __restrict__ V,
                                              unsigned short* __restrict__ Vt) {
  __shared__ unsigned short L[64 * 72];
  const int bh = blockIdx.y, t0 = blockIdx.x * 64;
  const int tid = threadIdx.x;
  const unsigned short* src = V + ((size_t)bh * SEQ + t0) * HD;
#pragma unroll
  for (int c = 0; c < 2; ++c) {
    int e = (c * 256 + tid) * 8;
    int tt = e >> 6, d = e & 63;
    us8_t v = *(const us8_t*)(src + tt * 64 + d);
#pragma unroll
    for (int i = 0; i < 8; ++i) L[(d + i) * 72 + tt] = v[i];
  }
  __syncthreads();
  unsigned short* dstb = Vt + (size_t)bh * HD * SEQ + t0;
#pragma unroll
  for (int c = 0; c < 2; ++c) {
    int e = (c * 256 + tid) * 8;
    int d = e >> 6, tt = e & 63;
    us8_t o = *(const us8_t*)&L[d * 72 + tt];
    *(us8_t*)(dstb + (size_t)d * SEQ + tt) = o;
  }
}

// ---------------- flash attention, split-S, 8 waves ----------------
// grid (32 q-tiles, 24 bh), 512 threads. Waves 0-3: s in [0,1024); 4-7: [1024,2048).
__global__ __launch_bounds__(512, 6) void flash_attn2(
    const unsigned short* __restrict__ Qb, const unsigned short* __restrict__ Kb,
    const unsigned short* __restrict__ Vt, const float* __restrict__ biasArr,
    const float* __restrict__ mask, const float* __restrict__ betaP,
    unsigned short* __restrict__ attn) {
  __shared__ __align__(16) char smem[49152];
  unsigned short* Klds = (unsigned short*)smem;            // [2][4096]
  unsigned short* Vlds = (unsigned short*)(smem + 16384);  // [2][4096]
  unsigned short* Plds = (unsigned short*)(smem + 32768);  // [8][1024]
  const int tid = threadIdx.x;
  const int w = tid >> 6, lane = tid & 63;
  const int g = w >> 2, wq = w & 3;
  const int quad = lane >> 4, l15 = lane & 15;
  const int bh = blockIdx.y;
  const int b = bh / NH, h = bh % NH;
  const int q0 = blockIdx.x * 64;
  const float betav = betaP[0];

  const unsigned short* qbase = Qb + ((size_t)bh * SEQ + q0 + wq * 16 + l15) * HD;
  bf8_t qf[2];
  qf[0] = *(const bf8_t*)(qbase + quad * 8);
  qf[1] = *(const bf8_t*)(qbase + 32 + quad * 8);

  union { us8_t u; bf8_t b; } ou;
#pragma unroll
  for (int i = 0; i < 8; ++i) ou.u[i] = 0x3F80;  // bf16 1.0
  const bf8_t ones = ou.b;

  float m_i[4];
  f4_t Oacc[4] = {};
  f4_t Lacc = {};
#pragma unroll
  for (int r = 0; r < 4; ++r) m_i[r] = -1e30f;

  unsigned short* Kg = Klds + g * 4096;
  unsigned short* Vg = Vlds + g * 4096;
  unsigned short* Pw = Plds + w * 1024;
  const unsigned short* KgBase = Kb + (size_t)bh * SEQ * HD;
  const unsigned short* VtBase = Vt + (size_t)bh * HD * SEQ;

  for (int it = 0; it < 16; ++it) {
    const int s0 = g * 1024 + it * 64;
    __syncthreads();
#pragma unroll
    for (int c = 0; c < 2; ++c) {
      int idx = (wq * 2 + c) * 512 + lane * 8;
      const unsigned short* gk = KgBase + (size_t)s0 * HD + idx;
      __builtin_amdgcn_global_load_lds((const __attribute__((address_space(1))) void*)gk,
          (__attribute__((address_space(3))) void*)&Kg[(wq * 2 + c) * 512], 16, 0, 0);
      int vrow = idx >> 6, vcol = idx & 63;
      const unsigned short* gv = VtBase + (size_t)vrow * SEQ + s0 + vcol;
      __builtin_amdgcn_global_load_lds((const __attribute__((address_space(1))) void*)gv,
          (__attribute__((address_space(3))) void*)&Vg[(wq * 2 + c) * 512], 16, 0, 0);
    }
    __builtin_amdgcn_s_waitcnt(0);
    __syncthreads();

    // S = Q K^T
    f4_t sacc[4];
#pragma unroll
    for (int st = 0; st < 4; ++st) {
      sacc[st] = (f4_t){0.f, 0.f, 0.f, 0.f};
#pragma unroll
      for (int ks = 0; ks < 2; ++ks) {
        bf8_t kf = *(const bf8_t*)&Kg[(st * 16 + l15) * 64 + ks * 32 + quad * 8];
        sacc[st] = __builtin_amdgcn_mfma_f32_16x16x32_bf16(qf[ks], kf, sacc[st], 0, 0, 0);
      }
    }

    // add beta*bias + mask (beta_bias dropped: softmax shift-invariant)
    float bb[4];
#pragma unroll
    for (int st = 0; st < 4; ++st)
      bb[st] = betav * biasArr[(size_t)bh * SEQ + s0 + st * 16 + l15];
#pragma unroll
    for (int r = 0; r < 4; ++r) {
      int q = q0 + wq * 16 + quad * 4 + r;
      const float* mrow = mask + ((size_t)b * SEQ + q) * SEQ + s0;
#pragma unroll
      for (int st = 0; st < 4; ++st)
        sacc[st][r] = sacc[st][r] + bb[st] + mrow[st * 16 + l15];
    }

    // online softmax: max via shuffles; sum via MFMA-with-ones below
#pragma unroll
    for (int r = 0; r < 4; ++r) {
      float mx = fmaxf(fmaxf(sacc[0][r], sacc[1][r]), fmaxf(sacc[2][r], sacc[3][r]));
#pragma unroll
      for (int off = 1; off < 16; off <<= 1) mx = fmaxf(mx, __shfl_xor(mx, off, 16));
      float mnew = fmaxf(m_i[r], mx);
      float alpha = __expf(m_i[r] - mnew);
      m_i[r] = mnew;
#pragma unroll
      for (int st = 0; st < 4; ++st) sacc[st][r] = __expf(sacc[st][r] - mnew);
#pragma unroll
      for (int dt = 0; dt < 4; ++dt) Oacc[dt][r] *= alpha;
      Lacc[r] *= alpha;
    }

    // P round-trip: C/D-layout -> LDS [q][s] -> A-layout
#pragma unroll
    for (int r = 0; r < 4; ++r)
#pragma unroll
      for (int st = 0; st < 4; ++st)
        Pw[(quad * 4 + r) * 64 + st * 16 + l15] = f2bf(sacc[st][r]);

#pragma unroll
    for (int ks = 0; ks < 2; ++ks) {
      bf8_t pf = *(const bf8_t*)&Pw[l15 * 64 + ks * 32 + quad * 8];
      Lacc = __builtin_amdgcn_mfma_f32_16x16x32_bf16(pf, ones, Lacc, 0, 0, 0);  // row sums
#pragma unroll
      for (int dt = 0; dt < 4; ++dt) {
        bf8_t vf = *(const bf8_t*)&Vg[(dt * 16 + l15) * 64 + ks * 32 + quad * 8];
        Oacc[dt] = __builtin_amdgcn_mfma_f32_16x16x32_bf16(pf, vf, Oacc[dt], 0, 0, 0);
      }
    }
  }

  // merge the two s-halves through LDS
  __syncthreads();  // last tile's LDS reads done before reuse
  float* O1 = (float*)smem;             // [4][16][64] fp32 = 16 KB
  float* ml1 = (float*)(smem + 16384);  // [4][16][2]
  if (g == 1) {
#pragma unroll
    for (int r = 0; r < 4; ++r) {
      int row = wq * 16 + quad * 4 + r;
#pragma unroll
      for (int dt = 0; dt < 4; ++dt) O1[row * 64 + dt * 16 + l15] = Oacc[dt][r];
      ml1[row * 2] = m_i[r];
      ml1[row * 2 + 1] = Lacc[r];
    }
  }
  __syncthreads();
  if (g == 0) {
#pragma unroll
    for (int r = 0; r < 4; ++r) {
      int row = wq * 16 + quad * 4 + r;
      float m1 = ml1[row * 2], l1 = ml1[row * 2 + 1];
      float M = fmaxf(m_i[r], m1);
      float w0 = __expf(m_i[r] - M), w1 = __expf(m1 - M);
      float inv = 1.0f / (Lacc[r] * w0 + l1 * w1);
      int q = q0 + row;
      unsigned short* orow = attn + ((size_t)b * SEQ + q) * E + h * HD;
#pragma unroll
      for (int dt = 0; dt < 4; ++dt)
        orow[dt * 16 + l15] = f2bf((Oacc[dt][r] * w0 + O1[row * 64 + dt * 16 + l15] * w1) * inv);
    }
  }
}

// ---------------- output projection GEMM -> fp32 out ----------------
__global__ __launch_bounds__(256) void gemm_out(
    const unsigned short* __restrict__ A, const unsigned short* __restrict__ Bw,
    const float* __restrict__ bo, float* __restrict__ out) {
  __shared__ unsigned short Alds[128 * 32];
  __shared__ unsigned short Blds[128 * 32];
  const int w = threadIdx.x >> 6, lane = threadIdx.x & 63;
  const int quad = lane >> 4, l15 = lane & 15;
  const int rowBase = blockIdx.x * 128;
  const int colBase = blockIdx.y * 128;
  const int wr = (w & 1) * 64, wc = (w >> 1) * 64;
  f4_t acc[4][4] = {};

  for (int k0 = 0; k0 < E; k0 += 32) {
    __syncthreads();
#pragma unroll
    for (int c = 0; c < 2; ++c) {
      int idx = (w * 2 + c) * 512 + lane * 8;
      const unsigned short* ga = A + (size_t)(rowBase + (idx >> 5)) * E + k0 + (idx & 31);
      __builtin_amdgcn_global_load_lds((const __attribute__((address_space(1))) void*)ga,
          (__attribute__((address_space(3))) void*)&Alds[(w * 2 + c) * 512], 16, 0, 0);
      const unsigned short* gb = Bw + (size_t)(colBase + (idx >> 5)) * E + k0 + (idx & 31);
      __builtin_amdgcn_global_load_lds((const __attribute__((address_space(1))) void*)gb,
          (__attribute__((address_space(3))) void*)&Blds[(w * 2 + c) * 512], 16, 0, 0);
    }
    __builtin_amdgcn_s_waitcnt(0);
    __syncthreads();
    bf8_t af[4], bfr[4];
#pragma unroll
    for (int mi = 0; mi < 4; ++mi)
      af[mi] = *(const bf8_t*)&Alds[(wr + mi * 16 + l15) * 32 + quad * 8];
#pragma unroll
    for (int ni = 0; ni < 4; ++ni)
      bfr[ni] = *(const bf8_t*)&Blds[(wc + ni * 16 + l15) * 32 + quad * 8];
#pragma unroll
    for (int mi = 0; mi < 4; ++mi)
#pragma unroll
      for (int ni = 0; ni < 4; ++ni)
        acc[mi][ni] = __builtin_amdgcn_mfma_f32_16x16x32_bf16(af[mi], bfr[ni], acc[mi][ni], 0, 0, 0);
  }

#pragma unroll
  for (int mi = 0; mi < 4; ++mi) {
#pragma unroll
    for (int ni = 0; ni < 4; ++ni) {
      int gn = colBase + wc + ni * 16 + l15;
      float bias = bo[gn];
#pragma unroll
      for (int r = 0; r < 4; ++r) {
        int gm = rowBase + wr + mi * 16 + quad * 4 + r;
        out[(size_t)gm * E + gn] = acc[mi][ni][r] + bias;
      }
    }
  }
}

extern "C" void kernel_launch(void* const* d_in, const int* in_sizes, int n_in,
                              void* d_out, int out_size, void* d_ws, size_t ws_size,
                              hipStream_t stream) {
  const float* hidden = (const float*)d_in[0];
  const float* mask = (const float*)d_in[1];
  const float* abias = (const float*)d_in[2];
  const float* Wq = (const float*)d_in[3];
  const float* bq = (const float*)d_in[4];
  const float* Wk = (const float*)d_in[5];
  const float* bk = (const float*)d_in[6];
  const float* Wv = (const float*)d_in[7];
  const float* bv = (const float*)d_in[8];
  const float* Wo = (const float*)d_in[9];
  const float* bo = (const float*)d_in[10];
  const float* beta = (const float*)d_in[11];
  float* out = (float*)d_out;

  char* ws = (char*)d_ws;
  // layout (bytes): Xbf 6291456 | Wqkv 3538944 | Wobf 1179648 | Q | K | V | Vt (each 6291456)
  unsigned short* Xbf = (unsigned short*)(ws);
  unsigned short* Wqkv = (unsigned short*)(ws + 6291456);
  unsigned short* Wobf = (unsigned short*)(ws + 9830400);
  unsigned short* Qbuf = (unsigned short*)(ws + 11010048);
  unsigned short* Kbuf = (unsigned short*)(ws + 17301504);
  unsigned short* Vbuf = (unsigned short*)(ws + 23592960);
  unsigned short* Vtb = (unsigned short*)(ws + 29884416);
  unsigned short* Attn = Xbf;  // Xbf dead after gemm_qkv; reuse for attn output

  cvt_all<<<2688, 256, 0, stream>>>(hidden, Wq, Wk, Wv, Wo, Xbf, Wqkv, Wobf);
  gemm_qkv<<<dim3(32, 18), 256, 0, stream>>>(Xbf, Wqkv, bq, bk, bv, Qbuf, Kbuf, Vbuf);
  vtrans<<<dim3(32, 24), 256, 0, stream>>>(Vbuf, Vtb);
  flash_attn2<<<dim3(32, 24), 512, 0, stream>>>(Qbuf, Kbuf, Vtb, abias, mask, beta, Attn);
  gemm_out<<<dim3(32, 6), 256, 0, stream>>>(Attn, Wobf, bo, out);
}

// Round 3
// 262.046 us; speedup vs baseline: 1.0746x; 1.0677x over previous
//
#include <hip/hip_runtime.h>
#include <hip/hip_bf16.h>

#define E 768
#define HD 64
#define NH 12
#define BSZ 2
#define SEQ 2048
#define M_ROWS (BSZ * SEQ)   // 4096
#define BH (BSZ * NH)        // 24

typedef float f4_t __attribute__((ext_vector_type(4)));
typedef __bf16 bf8_t __attribute__((ext_vector_type(8)));
typedef unsigned short us8_t __attribute__((ext_vector_type(8)));
typedef unsigned short us4_t __attribute__((ext_vector_type(4)));

__device__ inline unsigned short f2bf(float f) {
  union { float f; unsigned u; } v; v.f = f;
  unsigned u = v.u + 0x7FFFu + ((v.u >> 16) & 1u);
  return (unsigned short)(u >> 16);
}

// ---------------- fused fp32 -> bf16 convert for all 5 tensors ----------------
__global__ __launch_bounds__(256) void cvt_all(
    const float* __restrict__ X, const float* __restrict__ Wq,
    const float* __restrict__ Wk, const float* __restrict__ Wv,
    const float* __restrict__ Wo, unsigned short* __restrict__ Xbf,
    unsigned short* __restrict__ Wqkv, unsigned short* __restrict__ Wobf) {
  const int nW = E * E;  // 589824
  int id = blockIdx.x;
  const float* src;
  unsigned short* dst;
  float scale = 1.0f;
  int base;
  if (id < 1536) {
    src = X; dst = Xbf; base = id * 2048;
  } else {
    int r = id - 1536;
    int k = r / 288;
    int rb = r - k * 288;
    base = rb * 2048;
    if (k == 0)      { src = Wq; dst = Wqkv;          scale = 0.125f; }
    else if (k == 1) { src = Wk; dst = Wqkv + nW;     }
    else if (k == 2) { src = Wv; dst = Wqkv + 2 * nW; }
    else             { src = Wo; dst = Wobf;          }
  }
  int i = base + threadIdx.x * 8;
  const float4* s = (const float4*)(src + i);
  float4 a = s[0], b = s[1];
  us8_t o;
  o[0] = f2bf(a.x * scale); o[1] = f2bf(a.y * scale);
  o[2] = f2bf(a.z * scale); o[3] = f2bf(a.w * scale);
  o[4] = f2bf(b.x * scale); o[5] = f2bf(b.y * scale);
  o[6] = f2bf(b.z * scale); o[7] = f2bf(b.w * scale);
  *(us8_t*)(dst + i) = o;
}

// ---------------- fused QKV GEMM: C = X @ Wqkv^T ------
// Q,K written [bh][t][d]; V written TRANSPOSED [bh][d][t] (flash wants V^T).
__global__ __launch_bounds__(256) void gemm_qkv(
    const unsigned short* __restrict__ A, const unsigned short* __restrict__ Bw,
    const float* __restrict__ bq, const float* __restrict__ bk, const float* __restrict__ bv,
    unsigned short* __restrict__ Qb, unsigned short* __restrict__ Kb,
    unsigned short* __restrict__ Vtb) {
  __shared__ unsigned short Alds[128 * 32];
  __shared__ unsigned short Blds[128 * 32];
  const int w = threadIdx.x >> 6, lane = threadIdx.x & 63;
  const int quad = lane >> 4, l15 = lane & 15;
  const int rowBase = blockIdx.x * 128;
  const int colBase = blockIdx.y * 128;
  const int wr = (w & 1) * 64, wc = (w >> 1) * 64;
  f4_t acc[4][4] = {};

  for (int k0 = 0; k0 < E; k0 += 32) {
    __syncthreads();
#pragma unroll
    for (int c = 0; c < 2; ++c) {
      int idx = (w * 2 + c) * 512 + lane * 8;
      const unsigned short* ga = A + (size_t)(rowBase + (idx >> 5)) * E + k0 + (idx & 31);
      __builtin_amdgcn_global_load_lds((const __attribute__((address_space(1))) void*)ga,
          (__attribute__((address_space(3))) void*)&Alds[(w * 2 + c) * 512], 16, 0, 0);
      const unsigned short* gb = Bw + (size_t)(colBase + (idx >> 5)) * E + k0 + (idx & 31);
      __builtin_amdgcn_global_load_lds((const __attribute__((address_space(1))) void*)gb,
          (__attribute__((address_space(3))) void*)&Blds[(w * 2 + c) * 512], 16, 0, 0);
    }
    __builtin_amdgcn_s_waitcnt(0);
    __syncthreads();
    bf8_t af[4], bfr[4];
#pragma unroll
    for (int mi = 0; mi < 4; ++mi)
      af[mi] = *(const bf8_t*)&Alds[(wr + mi * 16 + l15) * 32 + quad * 8];
#pragma unroll
    for (int ni = 0; ni < 4; ++ni)
      bfr[ni] = *(const bf8_t*)&Blds[(wc + ni * 16 + l15) * 32 + quad * 8];
#pragma unroll
    for (int mi = 0; mi < 4; ++mi)
#pragma unroll
      for (int ni = 0; ni < 4; ++ni)
        acc[mi][ni] = __builtin_amdgcn_mfma_f32_16x16x32_bf16(af[mi], bfr[ni], acc[mi][ni], 0, 0, 0);
  }

  const int which = colBase / E;
  if (which < 2) {
    const float* biasP = (which == 0) ? bq : bk;
    unsigned short* dst = (which == 0) ? Qb : Kb;
    const float bscale = (which == 0) ? 0.125f : 1.0f;
#pragma unroll
    for (int mi = 0; mi < 4; ++mi) {
#pragma unroll
      for (int ni = 0; ni < 4; ++ni) {
        int gn = colBase + wc + ni * 16 + l15;
        int cn = gn - which * E;
        int h = cn >> 6, d = cn & 63;
        float bias = biasP[cn] * bscale;
#pragma unroll
        for (int r = 0; r < 4; ++r) {
          int gm = rowBase + wr + mi * 16 + quad * 4 + r;
          int b = gm >> 11, t = gm & 2047;
          dst[((size_t)(b * NH + h) * SEQ + t) * HD + d] = f2bf(acc[mi][ni][r] + bias);
        }
      }
    }
  } else {
    // V^T epilogue: [bh][d][t], 4 consecutive t per store (us4 packed)
#pragma unroll
    for (int mi = 0; mi < 4; ++mi) {
#pragma unroll
      for (int ni = 0; ni < 4; ++ni) {
        int cn = colBase - 2 * E + wc + ni * 16 + l15;  // 0..767
        int h = cn >> 6, d = cn & 63;
        float bias = bv[cn];
        int gm0 = rowBase + wr + mi * 16 + quad * 4;
        int b = gm0 >> 11, t = gm0 & 2047;
        us4_t o4;
#pragma unroll
        for (int r = 0; r < 4; ++r) o4[r] = f2bf(acc[mi][ni][r] + bias);
        *(us4_t*)&Vtb[((size_t)(b * NH + h) * HD + d) * SEQ + t] = o4;
      }
    }
  }
}

// ---------------- flash attention v3: S^T structure, swizzled LDS ----------------
// grid (32 q-tiles, 24 bh), 512 thr = 8 waves: wq=w&3 (q-subtile), g=w>>2 (s-half).
// Each lane owns ONE query (q = l15): softmax fully in-lane + 2 shfl_xor.
// All LDS tiles 64x64 bf16 with 16B-chunk XOR swizzle: conflict-free b128 access.
__global__ __launch_bounds__(512, 4) void flash_attn3(
    const unsigned short* __restrict__ Qb, const unsigned short* __restrict__ Kb,
    const unsigned short* __restrict__ Vt, const float* __restrict__ biasArr,
    const float* __restrict__ mask, const float* __restrict__ betaP,
    unsigned short* __restrict__ attn) {
  __shared__ __align__(16) char smem[49152];
  unsigned short* Klds = (unsigned short*)smem;            // [2][4096] (per s-group)
  unsigned short* Vlds = (unsigned short*)(smem + 16384);  // [2][4096]
  unsigned short* Plds = (unsigned short*)(smem + 32768);  // [8][1024] per-wave
  const int tid = threadIdx.x;
  const int w = tid >> 6, lane = tid & 63;
  const int g = w >> 2, wq = w & 3;
  const int quad = lane >> 4, l15 = lane & 15;
  const int bh = blockIdx.y;
  const int b = bh / NH, h = bh % NH;
  const int q0 = blockIdx.x * 64;
  const int q = q0 + wq * 16 + l15;  // this lane's query row
  const float betav = betaP[0];
  const int sw = l15 & 7;  // swizzle key for frag reads (row&7 == l15&7)

  // Q fragment (B-operand of K*Q^T: n=q=l15, k=d=quad*8+j)
  const unsigned short* qbase = Qb + ((size_t)bh * SEQ + q) * HD;
  bf8_t qf[2];
  qf[0] = *(const bf8_t*)(qbase + quad * 8);
  qf[1] = *(const bf8_t*)(qbase + 32 + quad * 8);

  float m_i = -1e30f, l_i = 0.f;
  f4_t Oacc[4] = {};  // O^T: row d = dt*16+quad*4+r, col q = l15

  unsigned short* Kg = Klds + g * 4096;
  unsigned short* Vg = Vlds + g * 4096;
  unsigned short* Pw = Plds + w * 1024;
  const unsigned short* KgBase = Kb + (size_t)bh * SEQ * HD;
  const unsigned short* VtBase = Vt + (size_t)bh * HD * SEQ;
  const float* maskRow = mask + ((size_t)b * SEQ + q) * SEQ;
  const float* biasRow = biasArr + (size_t)bh * SEQ;
  const int tg = wq * 64 + lane;  // 0..255 within s-group

  for (int it = 0; it < 16; ++it) {
    const int s0 = g * 1024 + it * 64;
    // stage K tile [s][d] and V^T tile [d][s] via VGPR round-trip (swizzled write)
    us8_t kreg[2], vreg[2];
#pragma unroll
    for (int c = 0; c < 2; ++c) {
      int eidx = (c * 256 + tg) * 8;
      int row = eidx >> 6, col = eidx & 63;
      kreg[c] = *(const us8_t*)(KgBase + (size_t)(s0 + row) * HD + col);
      vreg[c] = *(const us8_t*)(VtBase + (size_t)row * SEQ + s0 + col);
    }
    __syncthreads();  // previous iter's frag reads complete
#pragma unroll
    for (int c = 0; c < 2; ++c) {
      int eidx = (c * 256 + tg) * 8;
      int row = eidx >> 6, col = eidx & 63;
      int ph = row * 64 + ((((col >> 3) ^ (row & 7))) << 3);
      *(us8_t*)&Kg[ph] = kreg[c];
      *(us8_t*)&Vg[ph] = vreg[c];
    }
    __syncthreads();

    // S^T = K Q^T : A=K (m=s), B=Q^T (n=q). C/D: col=q=l15, row=s=st*16+quad*4+r
    f4_t sacc[4];
#pragma unroll
    for (int st = 0; st < 4; ++st) {
      sacc[st] = (f4_t){0.f, 0.f, 0.f, 0.f};
#pragma unroll
      for (int ks = 0; ks < 2; ++ks) {
        bf8_t kf = *(const bf8_t*)&Kg[(st * 16 + l15) * 64 + (((ks * 4 + quad) ^ sw) << 3)];
        sacc[st] = __builtin_amdgcn_mfma_f32_16x16x32_bf16(kf, qf[ks], sacc[st], 0, 0, 0);
      }
    }

    // + beta*bias[s] + mask[q][s]  (float4: r=0..3 are consecutive s)
#pragma unroll
    for (int st = 0; st < 4; ++st) {
      int sb = s0 + st * 16 + quad * 4;
      float4 b4 = *(const float4*)&biasRow[sb];
      float4 m4 = *(const float4*)&maskRow[sb];
      sacc[st][0] += betav * b4.x + m4.x;
      sacc[st][1] += betav * b4.y + m4.y;
      sacc[st][2] += betav * b4.z + m4.z;
      sacc[st][3] += betav * b4.w + m4.w;
    }

    // online softmax: lane owns q; 16 s-values in-lane, reduce across quads via 2 shfl
    float mx = sacc[0][0];
#pragma unroll
    for (int st = 0; st < 4; ++st)
#pragma unroll
      for (int r = 0; r < 4; ++r) mx = fmaxf(mx, sacc[st][r]);
    mx = fmaxf(mx, __shfl_xor(mx, 16, 64));
    mx = fmaxf(mx, __shfl_xor(mx, 32, 64));
    float mnew = fmaxf(m_i, mx);
    float alpha = __expf(m_i - mnew);
    float lsum = 0.f;
#pragma unroll
    for (int st = 0; st < 4; ++st)
#pragma unroll
      for (int r = 0; r < 4; ++r) {
        float p = __expf(sacc[st][r] - mnew);
        sacc[st][r] = p;
        lsum += p;
      }
    lsum += __shfl_xor(lsum, 16, 64);
    lsum += __shfl_xor(lsum, 32, 64);
    m_i = mnew;
    l_i = l_i * alpha + lsum;
#pragma unroll
    for (int dt = 0; dt < 4; ++dt)
#pragma unroll
      for (int r = 0; r < 4; ++r) Oacc[dt][r] *= alpha;

    // P round-trip: store P[q][s] (4x ds_write_b64, swizzled), reread as B-op frags
#pragma unroll
    for (int st = 0; st < 4; ++st) {
      us4_t p4;
      p4[0] = f2bf(sacc[st][0]); p4[1] = f2bf(sacc[st][1]);
      p4[2] = f2bf(sacc[st][2]); p4[3] = f2bf(sacc[st][3]);
      int col = st * 16 + quad * 4;
      int addr = l15 * 64 + ((((col >> 3) ^ sw)) << 3) + (col & 7);
      *(us4_t*)&Pw[addr] = p4;
    }

    // O^T += V^T P^T : A=V^T (m=d), B=P^T (n=q)
#pragma unroll
    for (int ks = 0; ks < 2; ++ks) {
      bf8_t pf = *(const bf8_t*)&Pw[l15 * 64 + (((ks * 4 + quad) ^ sw) << 3)];
#pragma unroll
      for (int dt = 0; dt < 4; ++dt) {
        bf8_t vf = *(const bf8_t*)&Vg[(dt * 16 + l15) * 64 + (((ks * 4 + quad) ^ sw) << 3)];
        Oacc[dt] = __builtin_amdgcn_mfma_f32_16x16x32_bf16(vf, pf, Oacc[dt], 0, 0, 0);
      }
    }
  }

  // merge the two s-halves through LDS
  __syncthreads();
  float* Om = (float*)smem;               // [4 wq][64 d][16 q] = 16 KB
  float* ml = (float*)(smem + 16384);     // [4 wq][16 q][2]
  if (g == 1) {
#pragma unroll
    for (int dt = 0; dt < 4; ++dt)
#pragma unroll
      for (int r = 0; r < 4; ++r)
        Om[(wq * 64 + dt * 16 + quad * 4 + r) * 16 + l15] = Oacc[dt][r];
    if (quad == 0) {
      ml[(wq * 16 + l15) * 2] = m_i;
      ml[(wq * 16 + l15) * 2 + 1] = l_i;
    }
  }
  __syncthreads();
  if (g == 0) {
    float m1 = ml[(wq * 16 + l15) * 2], l1v = ml[(wq * 16 + l15) * 2 + 1];
    float M = fmaxf(m_i, m1);
    float w0 = __expf(m_i - M), w1 = __expf(m1 - M);
    float inv = 1.0f / (l_i * w0 + l1v * w1);
    unsigned short* orow = attn + ((size_t)b * SEQ + q) * E + h * HD;
#pragma unroll
    for (int dt = 0; dt < 4; ++dt) {
      us4_t o4;
#pragma unroll
      for (int r = 0; r < 4; ++r) {
        float o1 = Om[(wq * 64 + dt * 16 + quad * 4 + r) * 16 + l15];
        o4[r] = f2bf((Oacc[dt][r] * w0 + o1 * w1) * inv);
      }
      *(us4_t*)&orow[dt * 16 + quad * 4] = o4;
    }
  }
}

// ---------------- output projection GEMM -> fp32 out ----------------
__global__ __launch_bounds__(256) void gemm_out(
    const unsigned short* __restrict__ A, const unsigned short* __restrict__ Bw,
    const float* __restrict__ bo, float* __restrict__ out) {
  __shared__ unsigned short Alds[128 * 32];
  __shared__ unsigned short Blds[128 * 32];
  const int w = threadIdx.x >> 6, lane = threadIdx.x & 63;
  const int quad = lane >> 4, l15 = lane & 15;
  const int rowBase = blockIdx.x * 128;
  const int colBase = blockIdx.y * 128;
  const int wr = (w & 1) * 64, wc = (w >> 1) * 64;
  f4_t acc[4][4] = {};

  for (int k0 = 0; k0 < E; k0 += 32) {
    __syncthreads();
#pragma unroll
    for (int c = 0; c < 2; ++c) {
      int idx = (w * 2 + c) * 512 + lane * 8;
      const unsigned short* ga = A + (size_t)(rowBase + (idx >> 5)) * E + k0 + (idx & 31);
      __builtin_amdgcn_global_load_lds((const __attribute__((address_space(1))) void*)ga,
          (__attribute__((address_space(3))) void*)&Alds[(w * 2 + c) * 512], 16, 0, 0);
      const unsigned short* gb = Bw + (size_t)(colBase + (idx >> 5)) * E + k0 + (idx & 31);
      __builtin_amdgcn_global_load_lds((const __attribute__((address_space(1))) void*)gb,
          (__attribute__((address_space(3))) void*)&Blds[(w * 2 + c) * 512], 16, 0, 0);
    }
    __builtin_amdgcn_s_waitcnt(0);
    __syncthreads();
    bf8_t af[4], bfr[4];
#pragma unroll
    for (int mi = 0; mi < 4; ++mi)
      af[mi] = *(const bf8_t*)&Alds[(wr + mi * 16 + l15) * 32 + quad * 8];
#pragma unroll
    for (int ni = 0; ni < 4; ++ni)
      bfr[ni] = *(const bf8_t*)&Blds[(wc + ni * 16 + l15) * 32 + quad * 8];
#pragma unroll
    for (int mi = 0; mi < 4; ++mi)
#pragma unroll
      for (int ni = 0; ni < 4; ++ni)
        acc[mi][ni] = __builtin_amdgcn_mfma_f32_16x16x32_bf16(af[mi], bfr[ni], acc[mi][ni], 0, 0, 0);
  }

#pragma unroll
  for (int mi = 0; mi < 4; ++mi) {
#pragma unroll
    for (int ni = 0; ni < 4; ++ni) {
      int gn = colBase + wc + ni * 16 + l15;
      float bias = bo[gn];
#pragma unroll
      for (int r = 0; r < 4; ++r) {
        int gm = rowBase + wr + mi * 16 + quad * 4 + r;
        out[(size_t)gm * E + gn] = acc[mi][ni][r] + bias;
      }
    }
  }
}

extern "C" void kernel_launch(void* const* d_in, const int* in_sizes, int n_in,
                              void* d_out, int out_size, void* d_ws, size_t ws_size,
                              hipStream_t stream) {
  const float* hidden = (const float*)d_in[0];
  const float* mask = (const float*)d_in[1];
  const float* abias = (const float*)d_in[2];
  const float* Wq = (const float*)d_in[3];
  const float* bq = (const float*)d_in[4];
  const float* Wk = (const float*)d_in[5];
  const float* bk = (const float*)d_in[6];
  const float* Wv = (const float*)d_in[7];
  const float* bv = (const float*)d_in[8];
  const float* Wo = (const float*)d_in[9];
  const float* bo = (const float*)d_in[10];
  const float* beta = (const float*)d_in[11];
  float* out = (float*)d_out;

  char* ws = (char*)d_ws;
  // layout (bytes): Xbf 6291456 | Wqkv 3538944 | Wobf 1179648 | Q | K | Vt (each 6291456)
  unsigned short* Xbf = (unsigned short*)(ws);
  unsigned short* Wqkv = (unsigned short*)(ws + 6291456);
  unsigned short* Wobf = (unsigned short*)(ws + 9830400);
  unsigned short* Qbuf = (unsigned short*)(ws + 11010048);
  unsigned short* Kbuf = (unsigned short*)(ws + 17301504);
  unsigned short* Vtb = (unsigned short*)(ws + 23592960);
  unsigned short* Attn = Xbf;  // Xbf dead after gemm_qkv; reuse for attn output

  cvt_all<<<2688, 256, 0, stream>>>(hidden, Wq, Wk, Wv, Wo, Xbf, Wqkv, Wobf);
  gemm_qkv<<<dim3(32, 18), 256, 0, stream>>>(Xbf, Wqkv, bq, bk, bv, Qbuf, Kbuf, Vtb);
  flash_attn3<<<dim3(32, 24), 512, 0, stream>>>(Qbuf, Kbuf, Vtb, abias, mask, beta, Attn);
  gemm_out<<<dim3(32, 6), 256, 0, stream>>>(Attn, Wobf, bo, out);
}